// Round 1
// baseline (423.151 us; speedup 1.0000x reference)
//
#include <hip/hip_runtime.h>
#include <hip/hip_fp16.h>

#define DIMC 768
#define NH 4
#define HD 192
#define SEQ 2048
#define NBATCH 8
#define SCALE_F 0.07216878364870323f /* 192^-0.5 */

typedef _Float16 f16x8 __attribute__((ext_vector_type(8)));
typedef _Float16 f16x4 __attribute__((ext_vector_type(4)));
typedef float    f32x4 __attribute__((ext_vector_type(4)));

__device__ __forceinline__ f32x4 mfma16(f16x8 a, f16x8 b, f32x4 c) {
    return __builtin_amdgcn_mfma_f32_16x16x32_f16(a, b, c, 0, 0, 0);
}

// ---------------------------------------------------------------------------
// GEMM: Y = A @ W^T   (A: [M=16384][768] fp32 or fp16, W: [768][768] fp32)
// MODE 0: out fp16, head-split  [b,h,n,d]           (Q,K projections)
// MODE 1: out fp16, head-split transposed [b,h,d,n] (V projection)
// MODE 2: out fp32 d_out [b,n,c] + bias             (final projection)
// tile 128x128, BK=32, 256 thr = 4 waves (2x2), wave tile 64x64 (4x4 frags)
// ---------------------------------------------------------------------------
template<int MODE, bool AHALF>
__global__ __launch_bounds__(256, 2)
void gemm_bt(const void* __restrict__ Aptr, const float* __restrict__ W,
             void* __restrict__ Yptr, const float* __restrict__ bias)
{
    // pad to 40 halves (80 B row stride -> 20 words, conflict-free-ish reads)
    __shared__ __attribute__((aligned(16))) _Float16 As[128][40];
    __shared__ __attribute__((aligned(16))) _Float16 Bs[128][40];

    const int tid  = threadIdx.x;
    const int wid  = tid >> 6;
    const int lane = tid & 63;
    const int l15  = lane & 15;
    const int l4   = lane >> 4;
    const int wr   = wid >> 1;
    const int wc   = wid & 1;
    const int m0   = blockIdx.x * 128;
    const int n0   = blockIdx.y * 128;

    const float*    Af = (const float*)Aptr;
    const _Float16* Ah = (const _Float16*)Aptr;

    f32x4 acc[4][4];
    #pragma unroll
    for (int m = 0; m < 4; ++m)
        #pragma unroll
        for (int n = 0; n < 4; ++n)
            acc[m][n] = (f32x4){0.f, 0.f, 0.f, 0.f};

    for (int kb = 0; kb < DIMC; kb += 32) {
        __syncthreads();
        #pragma unroll
        for (int p = 0; p < 4; ++p) {
            const int linear = p * 1024 + tid * 4;
            const int row = linear >> 5;
            const int kk  = linear & 31;
            f16x4 av;
            if (AHALF) {
                av = *(const f16x4*)(Ah + (size_t)(m0 + row) * DIMC + kb + kk);
            } else {
                const float4 v = *(const float4*)(Af + (size_t)(m0 + row) * DIMC + kb + kk);
                av = (f16x4){(_Float16)v.x, (_Float16)v.y, (_Float16)v.z, (_Float16)v.w};
            }
            *(f16x4*)(&As[row][kk]) = av;
            const float4 wv = *(const float4*)(W + (size_t)(n0 + row) * DIMC + kb + kk);
            f16x4 bv = {(_Float16)wv.x, (_Float16)wv.y, (_Float16)wv.z, (_Float16)wv.w};
            *(f16x4*)(&Bs[row][kk]) = bv;
        }
        __syncthreads();

        f16x8 af[4], bf[4];
        #pragma unroll
        for (int m = 0; m < 4; ++m)
            af[m] = *(const f16x8*)(&As[wr * 64 + m * 16 + l15][l4 * 8]);
        #pragma unroll
        for (int n = 0; n < 4; ++n)
            bf[n] = *(const f16x8*)(&Bs[wc * 64 + n * 16 + l15][l4 * 8]);
        #pragma unroll
        for (int m = 0; m < 4; ++m)
            #pragma unroll
            for (int n = 0; n < 4; ++n)
                acc[m][n] = mfma16(af[m], bf[n], acc[m][n]);
    }

    // epilogue: C frag layout col = lane&15, row = (lane>>4)*4 + reg
    #pragma unroll
    for (int m = 0; m < 4; ++m) {
        const int rbase = m0 + wr * 64 + m * 16 + l4 * 4;
        #pragma unroll
        for (int n = 0; n < 4; ++n) {
            const int c = n0 + wc * 64 + n * 16 + l15;
            if (MODE == 2) {
                float* out = (float*)Yptr;
                const float bv = bias[c];
                #pragma unroll
                for (int j = 0; j < 4; ++j)
                    out[(size_t)(rbase + j) * DIMC + c] = acc[m][n][j] + bv;
            } else {
                _Float16* out = (_Float16*)Yptr;
                const int h = c / HD;
                const int d = c - h * HD;
                #pragma unroll
                for (int j = 0; j < 4; ++j) {
                    const int r  = rbase + j;
                    const int b  = r >> 11;          // / SEQ
                    const int nn = r & (SEQ - 1);
                    size_t idx;
                    if (MODE == 0)
                        idx = ((size_t)(b * NH + h) * SEQ + nn) * HD + d;
                    else
                        idx = ((size_t)(b * NH + h) * HD + d) * SEQ + nn;
                    out[idx] = (_Float16)acc[m][n][j];
                }
            }
        }
    }
}

// ---------------------------------------------------------------------------
// Flash attention: per block (qtile of 128 rows, one (b,h)).
// 4 waves, each owns 32 Q-rows. K/V staged per 64-key tile in LDS.
// Qh,Kh: [bh][n][d] fp16;  Vt: [bh][d][n] fp16 (pre-transposed by proj).
// X out: [b][n][h*HD+d] fp16.
// ---------------------------------------------------------------------------
__global__ __launch_bounds__(256, 2)
void attn_fused(const _Float16* __restrict__ Qh, const _Float16* __restrict__ Kh,
                const _Float16* __restrict__ Vt, _Float16* __restrict__ X)
{
    __shared__ __attribute__((aligned(16))) _Float16 Ks[64][200];   // pad 192->200
    __shared__ __attribute__((aligned(16))) _Float16 Vs[192][72];   // pad 64->72
    __shared__ __attribute__((aligned(16))) _Float16 Ps[4][32][72]; // per-wave P

    const int tid  = threadIdx.x;
    const int wid  = tid >> 6;
    const int lane = tid & 63;
    const int l15  = lane & 15;
    const int l4   = lane >> 4;
    const int qt   = blockIdx.x;   // 0..15
    const int bh   = blockIdx.y;   // 0..31

    const size_t qkbase = (size_t)bh * SEQ * HD;
    const int q0 = qt * 128 + wid * 32;

    // Q fragments held in registers: rows q0..q0+32, K-dim = HD = 6 x 32
    f16x8 qf[2][6];
    #pragma unroll
    for (int mm = 0; mm < 2; ++mm)
        #pragma unroll
        for (int kk = 0; kk < 6; ++kk)
            qf[mm][kk] = *(const f16x8*)(Qh + qkbase +
                         (size_t)(q0 + mm * 16 + l15) * HD + kk * 32 + l4 * 8);

    f32x4 Oacc[2][12];
    #pragma unroll
    for (int mm = 0; mm < 2; ++mm)
        #pragma unroll
        for (int nd = 0; nd < 12; ++nd)
            Oacc[mm][nd] = (f32x4){0.f, 0.f, 0.f, 0.f};
    float mrow[2][4], lrow[2][4];
    #pragma unroll
    for (int mm = 0; mm < 2; ++mm)
        #pragma unroll
        for (int j = 0; j < 4; ++j) { mrow[mm][j] = -INFINITY; lrow[mm][j] = 0.f; }

    for (int kt = 0; kt < SEQ / 64; ++kt) {
        __syncthreads();
        // stage K tile [64 keys][192 d] (natural row-major)
        #pragma unroll
        for (int p = 0; p < 6; ++p) {
            const int linear = (p * 256 + tid) * 8;
            const int key = linear / 192;
            const int d   = linear - key * 192;
            const f16x8 kv = *(const f16x8*)(Kh + qkbase +
                              (size_t)(kt * 64 + key) * HD + d);
            *(f16x8*)(&Ks[key][d]) = kv;
        }
        // stage V^T tile [192 d][64 keys] (already transposed in global)
        #pragma unroll
        for (int p = 0; p < 6; ++p) {
            const int linear = (p * 256 + tid) * 8;
            const int d   = linear >> 6;
            const int key = linear & 63;
            const f16x8 vv = *(const f16x8*)(Vt + qkbase +
                              (size_t)d * SEQ + kt * 64 + key);
            *(f16x8*)(&Vs[d][key]) = vv;
        }
        __syncthreads();

        // S = Q K^T  (32 q-rows x 64 keys per wave)
        f32x4 sacc[2][4];
        #pragma unroll
        for (int mm = 0; mm < 2; ++mm)
            #pragma unroll
            for (int nn = 0; nn < 4; ++nn)
                sacc[mm][nn] = (f32x4){0.f, 0.f, 0.f, 0.f};
        #pragma unroll
        for (int kk = 0; kk < 6; ++kk) {
            #pragma unroll
            for (int nn = 0; nn < 4; ++nn) {
                const f16x8 kf = *(const f16x8*)(&Ks[nn * 16 + l15][kk * 32 + l4 * 8]);
                #pragma unroll
                for (int mm = 0; mm < 2; ++mm)
                    sacc[mm][nn] = mfma16(qf[mm][kk], kf, sacc[mm][nn]);
            }
        }

        // online softmax; row r = mm*16 + l4*4 + j, keys spread over lane&15 x nn
        #pragma unroll
        for (int mm = 0; mm < 2; ++mm) {
            #pragma unroll
            for (int j = 0; j < 4; ++j) {
                #pragma unroll
                for (int nn = 0; nn < 4; ++nn)
                    sacc[mm][nn][j] *= SCALE_F;
                float v = fmaxf(fmaxf(sacc[mm][0][j], sacc[mm][1][j]),
                                fmaxf(sacc[mm][2][j], sacc[mm][3][j]));
                v = fmaxf(v, __shfl_xor(v, 1));
                v = fmaxf(v, __shfl_xor(v, 2));
                v = fmaxf(v, __shfl_xor(v, 4));
                v = fmaxf(v, __shfl_xor(v, 8));
                const float mnew = fmaxf(mrow[mm][j], v);
                const float f    = __expf(mrow[mm][j] - mnew);
                mrow[mm][j] = mnew;
                float ssum = 0.f;
                #pragma unroll
                for (int nn = 0; nn < 4; ++nn) {
                    const float p = __expf(sacc[mm][nn][j] - mnew);
                    sacc[mm][nn][j] = p;
                    ssum += p;
                }
                ssum += __shfl_xor(ssum, 1);
                ssum += __shfl_xor(ssum, 2);
                ssum += __shfl_xor(ssum, 4);
                ssum += __shfl_xor(ssum, 8);
                lrow[mm][j] = lrow[mm][j] * f + ssum;
                #pragma unroll
                for (int nd = 0; nd < 12; ++nd)
                    Oacc[mm][nd][j] *= f;
            }
        }

        // P (C-frag layout) -> per-wave LDS -> reread as A-frags
        #pragma unroll
        for (int mm = 0; mm < 2; ++mm)
            #pragma unroll
            for (int nn = 0; nn < 4; ++nn)
                #pragma unroll
                for (int j = 0; j < 4; ++j)
                    Ps[wid][mm * 16 + l4 * 4 + j][nn * 16 + l15] =
                        (_Float16)sacc[mm][nn][j];
        asm volatile("s_waitcnt lgkmcnt(0)" ::: "memory");

        // O += P V   (A = P rows [q][key], B = V^T rows [d][key])
        #pragma unroll
        for (int kk2 = 0; kk2 < 2; ++kk2) {
            f16x8 pf[2];
            #pragma unroll
            for (int mm = 0; mm < 2; ++mm)
                pf[mm] = *(const f16x8*)(&Ps[wid][mm * 16 + l15][kk2 * 32 + l4 * 8]);
            #pragma unroll
            for (int nd = 0; nd < 12; ++nd) {
                const f16x8 vf = *(const f16x8*)(&Vs[nd * 16 + l15][kk2 * 32 + l4 * 8]);
                #pragma unroll
                for (int mm = 0; mm < 2; ++mm)
                    Oacc[mm][nd] = mfma16(pf[mm], vf, Oacc[mm][nd]);
            }
        }
    }

    // finalize: X[b][q][h*HD+d] = O / l
    const int b = bh >> 2;
    const int h = bh & 3;
    #pragma unroll
    for (int mm = 0; mm < 2; ++mm)
        #pragma unroll
        for (int j = 0; j < 4; ++j) {
            const float inv = 1.f / lrow[mm][j];
            const int qrow = q0 + mm * 16 + l4 * 4 + j;
            #pragma unroll
            for (int nd = 0; nd < 12; ++nd) {
                const int d = nd * 16 + l15;
                X[((size_t)b * SEQ + qrow) * DIMC + h * HD + d] =
                    (_Float16)(Oacc[mm][nd][j] * inv);
            }
        }
}

// ---------------------------------------------------------------------------
extern "C" void kernel_launch(void* const* d_in, const int* in_sizes, int n_in,
                              void* d_out, int out_size, void* d_ws, size_t ws_size,
                              hipStream_t stream)
{
    const float* q  = (const float*)d_in[0];
    const float* k  = (const float*)d_in[1];
    const float* v  = (const float*)d_in[2];
    const float* Wq = (const float*)d_in[3];
    const float* Wk = (const float*)d_in[4];
    const float* Wv = (const float*)d_in[5];
    const float* Wp = (const float*)d_in[6];
    const float* bp = (const float*)d_in[7];

    const size_t HSZ = (size_t)NBATCH * NH * SEQ * HD; // 12,582,912 elems
    _Float16* Qh = (_Float16*)d_ws;
    _Float16* Kh = Qh + HSZ;
    _Float16* Vt = Kh + HSZ;
    _Float16* X  = Vt + HSZ;  // total 4*HSZ*2B = 96 MB of ws

    dim3 blk(256);
    dim3 ggrid(128, 6);   // 16384/128 m-tiles x 768/128 n-tiles

    gemm_bt<0, false><<<ggrid, blk, 0, stream>>>((const void*)q, Wq, (void*)Qh, nullptr);
    gemm_bt<0, false><<<ggrid, blk, 0, stream>>>((const void*)k, Wk, (void*)Kh, nullptr);
    gemm_bt<1, false><<<ggrid, blk, 0, stream>>>((const void*)v, Wv, (void*)Vt, nullptr);
    attn_fused<<<dim3(16, 32), blk, 0, stream>>>(Qh, Kh, Vt, X);
    gemm_bt<2, true><<<ggrid, blk, 0, stream>>>((const void*)X, Wp, d_out, bp);
}

// Round 2
// 363.604 us; speedup vs baseline: 1.1638x; 1.1638x over previous
//
#include <hip/hip_runtime.h>
#include <hip/hip_fp16.h>

#define DIMC 768
#define NH 4
#define HD 192
#define SEQ 2048
#define NBATCH 8
#define SCALE_F 0.07216878364870323f /* 192^-0.5 */

typedef _Float16 f16x8 __attribute__((ext_vector_type(8)));
typedef _Float16 f16x4 __attribute__((ext_vector_type(4)));
typedef float    f32x4 __attribute__((ext_vector_type(4)));

__device__ __forceinline__ f32x4 mfma16(f16x8 a, f16x8 b, f32x4 c) {
    return __builtin_amdgcn_mfma_f32_16x16x32_f16(a, b, c, 0, 0, 0);
}

__device__ __forceinline__ void gl16(const void* g, void* l) {
    __builtin_amdgcn_global_load_lds(
        (const __attribute__((address_space(1))) unsigned int*)g,
        (__attribute__((address_space(3))) unsigned int*)l, 16, 0, 0);
}

// ---------------------------------------------------------------------------
// GEMM: Y = A @ W^T   (A: [16384][768] fp32/fp16, W: [768][768] fp32)
// MODE 0: Q -> fp16 [bh][n][d], scaled by `scale`
// MODE 1: K -> fp16 swizzled tile image [bh][kt][key*192 + (d ^ ((key&7)<<3))]
// MODE 3: V -> fp16 swizzled tile image [bh][kt][d*64  + (key ^ ((d&7)<<3))]
// MODE 2: fp32 d_out [b][n][c] + bias
// ---------------------------------------------------------------------------
template<int MODE, bool AHALF>
__global__ __launch_bounds__(256, 2)
void gemm_bt(const void* __restrict__ Aptr, const float* __restrict__ W,
             void* __restrict__ Yptr, const float* __restrict__ bias, float scale)
{
    __shared__ __attribute__((aligned(16))) _Float16 As[128][40];
    __shared__ __attribute__((aligned(16))) _Float16 Bs[128][40];

    const int tid  = threadIdx.x;
    const int wid  = tid >> 6;
    const int lane = tid & 63;
    const int l15  = lane & 15;
    const int l4   = lane >> 4;
    const int wr   = wid >> 1;
    const int wc   = wid & 1;
    const int m0   = blockIdx.x * 128;
    const int n0   = blockIdx.y * 128;

    const float*    Af = (const float*)Aptr;
    const _Float16* Ah = (const _Float16*)Aptr;

    f32x4 acc[4][4];
    #pragma unroll
    for (int m = 0; m < 4; ++m)
        #pragma unroll
        for (int n = 0; n < 4; ++n)
            acc[m][n] = (f32x4){0.f, 0.f, 0.f, 0.f};

    for (int kb = 0; kb < DIMC; kb += 32) {
        __syncthreads();
        #pragma unroll
        for (int p = 0; p < 4; ++p) {
            const int linear = p * 1024 + tid * 4;
            const int row = linear >> 5;
            const int kk  = linear & 31;
            f16x4 av;
            if (AHALF) {
                av = *(const f16x4*)(Ah + (size_t)(m0 + row) * DIMC + kb + kk);
            } else {
                const float4 v = *(const float4*)(Af + (size_t)(m0 + row) * DIMC + kb + kk);
                av = (f16x4){(_Float16)v.x, (_Float16)v.y, (_Float16)v.z, (_Float16)v.w};
            }
            *(f16x4*)(&As[row][kk]) = av;
            const float4 wv = *(const float4*)(W + (size_t)(n0 + row) * DIMC + kb + kk);
            f16x4 bv = {(_Float16)wv.x, (_Float16)wv.y, (_Float16)wv.z, (_Float16)wv.w};
            *(f16x4*)(&Bs[row][kk]) = bv;
        }
        __syncthreads();

        f16x8 af[4], bf[4];
        #pragma unroll
        for (int m = 0; m < 4; ++m)
            af[m] = *(const f16x8*)(&As[wr * 64 + m * 16 + l15][l4 * 8]);
        #pragma unroll
        for (int n = 0; n < 4; ++n)
            bf[n] = *(const f16x8*)(&Bs[wc * 64 + n * 16 + l15][l4 * 8]);
        #pragma unroll
        for (int m = 0; m < 4; ++m)
            #pragma unroll
            for (int n = 0; n < 4; ++n)
                acc[m][n] = mfma16(af[m], bf[n], acc[m][n]);
    }

    // epilogue: C frag layout row = (lane>>4)*4 + reg (A-dim), col = lane&15 (B-dim)
    #pragma unroll
    for (int m = 0; m < 4; ++m) {
        const int rbase = m0 + wr * 64 + m * 16 + l4 * 4;
        #pragma unroll
        for (int n = 0; n < 4; ++n) {
            const int c = n0 + wc * 64 + n * 16 + l15;
            if (MODE == 2) {
                float* out = (float*)Yptr;
                const float bv = bias[c];
                #pragma unroll
                for (int j = 0; j < 4; ++j)
                    out[(size_t)(rbase + j) * DIMC + c] = acc[m][n][j] + bv;
            } else {
                _Float16* out = (_Float16*)Yptr;
                const int h = c / HD;
                const int d = c - h * HD;
                #pragma unroll
                for (int j = 0; j < 4; ++j) {
                    const int r   = rbase + j;
                    const int b   = r >> 11;           // / SEQ
                    const int nn  = r & (SEQ - 1);
                    const int kt  = nn >> 6;
                    const int key = nn & 63;
                    const size_t tb = ((size_t)(b * NH + h) * 32 + kt) * 12288;
                    size_t idx;
                    if (MODE == 0)
                        idx = ((size_t)(b * NH + h) * SEQ + nn) * HD + d;
                    else if (MODE == 1)
                        idx = tb + (size_t)key * HD + (d ^ ((key & 7) << 3));
                    else // MODE 3
                        idx = tb + (size_t)d * 64 + (key ^ ((d & 7) << 3));
                    out[idx] = (_Float16)(acc[m][n][j] * scale);
                }
            }
        }
    }
}

// ---------------------------------------------------------------------------
// Flash attention, pipelined:
//  grid 256 (1 block/CU), 512 thr = 8 waves, q-tile 256 rows (32/wave).
//  K/V double-buffered in LDS via global_load_lds from pre-swizzled images.
//  Counted vmcnt(6): next tile's 6 loads stay in flight across barriers.
//  2 raw s_barriers per tile, setprio around MFMA, defer-max softmax.
// ---------------------------------------------------------------------------
__global__ __launch_bounds__(512, 2)
void attn2(const _Float16* __restrict__ Qh, const _Float16* __restrict__ Kimg,
           const _Float16* __restrict__ Vimg, _Float16* __restrict__ X)
{
    __shared__ __attribute__((aligned(16))) _Float16 Kbuf[2][12288];
    __shared__ __attribute__((aligned(16))) _Float16 Vbuf[2][12288];
    __shared__ __attribute__((aligned(16))) _Float16 Ps[8][32][72];

    const int tid  = threadIdx.x;
    const int wid  = tid >> 6;
    const int lane = tid & 63;
    const int l15  = lane & 15;
    const int l4   = lane >> 4;

    // XCD swizzle: each XCD owns 4 consecutive bh (K/V panels ~6MB -> its L2/L3)
    const int bid = blockIdx.x;
    const int swz = (bid & 7) * 32 + (bid >> 3);
    const int qt  = swz & 7;
    const int bh  = swz >> 3;

    const unsigned char* Kt0 = (const unsigned char*)Kimg + (size_t)bh * 32 * 24576;
    const unsigned char* Vt0 = (const unsigned char*)Vimg + (size_t)bh * 32 * 24576;

    // prologue: stage tile 0 into buf 0 (6 global_load_lds, 16B/lane)
    #pragma unroll
    for (int s = 0; s < 3; ++s) {
        gl16(Kt0 + s * 8192 + wid * 1024 + lane * 16, &Kbuf[0][s * 4096 + wid * 512]);
        gl16(Vt0 + s * 8192 + wid * 1024 + lane * 16, &Vbuf[0][s * 4096 + wid * 512]);
    }

    // Q fragments in registers (scale pre-folded by projection)
    const int q0 = qt * 256 + wid * 32;
    const size_t qbase = (size_t)bh * SEQ * HD;
    f16x8 qf[2][6];
    #pragma unroll
    for (int mm = 0; mm < 2; ++mm)
        #pragma unroll
        for (int kk = 0; kk < 6; ++kk)
            qf[mm][kk] = *(const f16x8*)(Qh + qbase +
                         (size_t)(q0 + mm * 16 + l15) * HD + kk * 32 + l4 * 8);

    f32x4 Oacc[2][12];
    #pragma unroll
    for (int mm = 0; mm < 2; ++mm)
        #pragma unroll
        for (int nd = 0; nd < 12; ++nd)
            Oacc[mm][nd] = (f32x4){0.f, 0.f, 0.f, 0.f};
    float mrow[2][4], lrow[2][4];
    #pragma unroll
    for (int mm = 0; mm < 2; ++mm)
        #pragma unroll
        for (int j = 0; j < 4; ++j) { mrow[mm][j] = -INFINITY; lrow[mm][j] = 0.f; }

    for (int kt = 0; kt < SEQ / 64; ++kt) {
        const int cur = kt & 1;
        // issue next tile's loads into the other buffer (its readers passed
        // the end-barrier of the previous iteration)
        if (kt < SEQ / 64 - 1) {
            const unsigned char* Kn = Kt0 + (size_t)(kt + 1) * 24576;
            const unsigned char* Vn = Vt0 + (size_t)(kt + 1) * 24576;
            #pragma unroll
            for (int s = 0; s < 3; ++s) {
                gl16(Kn + s * 8192 + wid * 1024 + lane * 16, &Kbuf[cur ^ 1][s * 4096 + wid * 512]);
                gl16(Vn + s * 8192 + wid * 1024 + lane * 16, &Vbuf[cur ^ 1][s * 4096 + wid * 512]);
            }
            asm volatile("s_waitcnt vmcnt(6)" ::: "memory");  // tile kt landed, 6 in flight
        } else {
            asm volatile("s_waitcnt vmcnt(0)" ::: "memory");  // last tile: drain
        }
        __builtin_amdgcn_s_barrier();           // everyone's tile-kt data present
        __builtin_amdgcn_sched_barrier(0);

        const _Float16* Kc = &Kbuf[cur][0];
        const _Float16* Vc = &Vbuf[cur][0];

        // ---- S = Q K^T (swizzled K reads, conflict-free) ----
        f32x4 sacc[2][4];
        #pragma unroll
        for (int mm = 0; mm < 2; ++mm)
            #pragma unroll
            for (int nn = 0; nn < 4; ++nn)
                sacc[mm][nn] = (f32x4){0.f, 0.f, 0.f, 0.f};
        __builtin_amdgcn_s_setprio(1);
        #pragma unroll
        for (int kk = 0; kk < 6; ++kk) {
            #pragma unroll
            for (int nn = 0; nn < 4; ++nn) {
                const int key = nn * 16 + l15;
                const f16x8 kf = *(const f16x8*)(Kc + (size_t)key * HD +
                                  ((kk * 32 + l4 * 8) ^ ((key & 7) << 3)));
                sacc[0][nn] = mfma16(qf[0][kk], kf, sacc[0][nn]);
                sacc[1][nn] = mfma16(qf[1][kk], kf, sacc[1][nn]);
            }
        }
        __builtin_amdgcn_s_setprio(0);

        // ---- online softmax (defer-max: skip rescale when max didn't grow) ----
        float vmax[2][4];
        bool need = false;
        #pragma unroll
        for (int mm = 0; mm < 2; ++mm)
            #pragma unroll
            for (int j = 0; j < 4; ++j) {
                float v = fmaxf(fmaxf(sacc[mm][0][j], sacc[mm][1][j]),
                                fmaxf(sacc[mm][2][j], sacc[mm][3][j]));
                v = fmaxf(v, __shfl_xor(v, 1));
                v = fmaxf(v, __shfl_xor(v, 2));
                v = fmaxf(v, __shfl_xor(v, 4));
                v = fmaxf(v, __shfl_xor(v, 8));
                vmax[mm][j] = v;
                need |= (v > mrow[mm][j]);
            }
        if (__any(need)) {
            #pragma unroll
            for (int mm = 0; mm < 2; ++mm)
                #pragma unroll
                for (int j = 0; j < 4; ++j) {
                    const float mnew = fmaxf(mrow[mm][j], vmax[mm][j]);
                    const float f    = __expf(mrow[mm][j] - mnew);
                    mrow[mm][j] = mnew;
                    lrow[mm][j] *= f;
                    #pragma unroll
                    for (int nd = 0; nd < 12; ++nd)
                        Oacc[mm][nd][j] *= f;
                }
        }
        #pragma unroll
        for (int mm = 0; mm < 2; ++mm)
            #pragma unroll
            for (int j = 0; j < 4; ++j) {
                float ssum = 0.f;
                #pragma unroll
                for (int nn = 0; nn < 4; ++nn) {
                    const float p = __expf(sacc[mm][nn][j] - mrow[mm][j]);
                    sacc[mm][nn][j] = p;
                    ssum += p;
                }
                ssum += __shfl_xor(ssum, 1);
                ssum += __shfl_xor(ssum, 2);
                ssum += __shfl_xor(ssum, 4);
                ssum += __shfl_xor(ssum, 8);
                lrow[mm][j] += ssum;
            }

        // P (C-frag) -> per-wave LDS -> reread as A-frags (own-wave only)
        #pragma unroll
        for (int mm = 0; mm < 2; ++mm)
            #pragma unroll
            for (int nn = 0; nn < 4; ++nn)
                #pragma unroll
                for (int j = 0; j < 4; ++j)
                    Ps[wid][mm * 16 + l4 * 4 + j][nn * 16 + l15] =
                        (_Float16)sacc[mm][nn][j];
        asm volatile("s_waitcnt lgkmcnt(0)" ::: "memory");
        __builtin_amdgcn_sched_barrier(0);

        // ---- O += P V (swizzled V reads, conflict-free) ----
        __builtin_amdgcn_s_setprio(1);
        #pragma unroll
        for (int kk2 = 0; kk2 < 2; ++kk2) {
            f16x8 pf[2];
            #pragma unroll
            for (int mm = 0; mm < 2; ++mm)
                pf[mm] = *(const f16x8*)(&Ps[wid][mm * 16 + l15][kk2 * 32 + l4 * 8]);
            #pragma unroll
            for (int nd = 0; nd < 12; ++nd) {
                const int d = nd * 16 + l15;
                const f16x8 vfr = *(const f16x8*)(Vc + (size_t)d * 64 +
                                   ((kk2 * 32 + l4 * 8) ^ ((d & 7) << 3)));
                Oacc[0][nd] = mfma16(pf[0], vfr, Oacc[0][nd]);
                Oacc[1][nd] = mfma16(pf[1], vfr, Oacc[1][nd]);
            }
        }
        __builtin_amdgcn_s_setprio(0);

        __builtin_amdgcn_s_barrier();           // all reads of buf[cur] done
        __builtin_amdgcn_sched_barrier(0);
    }

    // finalize: X[b][q][h*HD+d] = O / l
    const int b = bh >> 2;
    const int h = bh & 3;
    #pragma unroll
    for (int mm = 0; mm < 2; ++mm)
        #pragma unroll
        for (int j = 0; j < 4; ++j) {
            const float inv = 1.f / lrow[mm][j];
            const int qrow = q0 + mm * 16 + l4 * 4 + j;
            #pragma unroll
            for (int nd = 0; nd < 12; ++nd) {
                const int d = nd * 16 + l15;
                X[((size_t)b * SEQ + qrow) * DIMC + h * HD + d] =
                    (_Float16)(Oacc[mm][nd][j] * inv);
            }
        }
}

// ---------------------------------------------------------------------------
extern "C" void kernel_launch(void* const* d_in, const int* in_sizes, int n_in,
                              void* d_out, int out_size, void* d_ws, size_t ws_size,
                              hipStream_t stream)
{
    const float* q  = (const float*)d_in[0];
    const float* k  = (const float*)d_in[1];
    const float* v  = (const float*)d_in[2];
    const float* Wq = (const float*)d_in[3];
    const float* Wk = (const float*)d_in[4];
    const float* Wv = (const float*)d_in[5];
    const float* Wp = (const float*)d_in[6];
    const float* bp = (const float*)d_in[7];

    const size_t HSZ = (size_t)NBATCH * NH * SEQ * HD; // 12,582,912 elems
    _Float16* Qh   = (_Float16*)d_ws;
    _Float16* Kimg = Qh + HSZ;
    _Float16* Vimg = Kimg + HSZ;
    _Float16* X    = Vimg + HSZ;  // total 96 MB of ws

    dim3 blk(256);
    dim3 ggrid(128, 6);

    gemm_bt<0, false><<<ggrid, blk, 0, stream>>>((const void*)q, Wq, (void*)Qh, nullptr, SCALE_F);
    gemm_bt<1, false><<<ggrid, blk, 0, stream>>>((const void*)k, Wk, (void*)Kimg, nullptr, 1.0f);
    gemm_bt<3, false><<<ggrid, blk, 0, stream>>>((const void*)v, Wv, (void*)Vimg, nullptr, 1.0f);
    attn2<<<dim3(256), dim3(512), 0, stream>>>(Qh, Kimg, Vimg, X);
    gemm_bt<2, true><<<ggrid, blk, 0, stream>>>((const void*)X, Wp, d_out, bp, 1.0f);
}

// Round 4
// 316.817 us; speedup vs baseline: 1.3356x; 1.1477x over previous
//
#include <hip/hip_runtime.h>
#include <hip/hip_fp16.h>

#define DIMC 768
#define NH 4
#define HD 192
#define SEQ 2048
#define NBATCH 8
#define SCALE_F 0.07216878364870323f  /* 192^-0.5 */
#define LOG2E   1.4426950408889634f
#define DEFER_THR 8.0f                /* log2-domain defer-max threshold */

typedef _Float16 f16x8 __attribute__((ext_vector_type(8)));
typedef _Float16 f16x4 __attribute__((ext_vector_type(4)));
typedef float    f32x4 __attribute__((ext_vector_type(4)));

__device__ __forceinline__ f32x4 mfma16(f16x8 a, f16x8 b, f32x4 c) {
    return __builtin_amdgcn_mfma_f32_16x16x32_f16(a, b, c, 0, 0, 0);
}
__device__ __forceinline__ void gl16(const void* g, void* l) {
    __builtin_amdgcn_global_load_lds(
        (const __attribute__((address_space(1))) unsigned int*)g,
        (__attribute__((address_space(3))) unsigned int*)l, 16, 0, 0);
}
__device__ __forceinline__ float exp2_hw(float x) {
    return __builtin_amdgcn_exp2f(x);   // v_exp_f32 (base-2)
}

// ---------------------------------------------------------------------------
// cvt_w: fp32 W[768][768] -> fp16 pre-swizzled tile images.
// Image layout: ((nt*12 + kb)*128 + r)*64 + (c ^ ((r&7)<<3)),
//   nt = row>>7, r = row&127, kb = col>>6, c = col&63.
// ---------------------------------------------------------------------------
__global__ __launch_bounds__(256)
void cvt_w(const float* __restrict__ w0, const float* __restrict__ w1,
           const float* __restrict__ w2, const float* __restrict__ w3,
           _Float16* __restrict__ o0, _Float16* __restrict__ o1,
           _Float16* __restrict__ o2, _Float16* __restrict__ o3)
{
    const float* src = (blockIdx.y == 0) ? w0 : (blockIdx.y == 1) ? w1
                     : (blockIdx.y == 2) ? w2 : w3;
    _Float16* dst = (blockIdx.y == 0) ? o0 : (blockIdx.y == 1) ? o1
                  : (blockIdx.y == 2) ? o2 : o3;
    const int e   = blockIdx.x * 256 + threadIdx.x;   // 0..147455 (quads)
    const int row = e / 192;
    const int col = (e - row * 192) * 4;
    const float4 v = *(const float4*)(src + (size_t)row * DIMC + col);
    const int nt = row >> 7, r = row & 127, kb = col >> 6, c = col & 63;
    f16x4 h = {(_Float16)v.x, (_Float16)v.y, (_Float16)v.z, (_Float16)v.w};
    *(f16x4*)(dst + ((size_t)(nt * 12 + kb) * 128 + r) * 64 + (c ^ ((r & 7) << 3))) = h;
}

// ---------------------------------------------------------------------------
// Shared MFMA compute phase for the 128x128 BK=64 GEMM (4 waves, 2x2).
// As/Bs: [128][64] halves, XOR-swizzled: col ^ ((row&7)<<3).
// ---------------------------------------------------------------------------
__device__ __forceinline__ void gemm_compute(const _Float16* As, const _Float16* Bs,
                                             int wr, int wc, int l15, int l4,
                                             f32x4 acc[4][4])
{
    #pragma unroll
    for (int ks = 0; ks < 2; ++ks) {
        const int cb = (ks * 32 + l4 * 8) ^ ((l15 & 7) << 3);
        f16x8 af[4], bf[4];
        #pragma unroll
        for (int m = 0; m < 4; ++m)
            af[m] = *(const f16x8*)(As + (size_t)(wr * 64 + m * 16 + l15) * 64 + cb);
        #pragma unroll
        for (int n = 0; n < 4; ++n)
            bf[n] = *(const f16x8*)(Bs + (size_t)(wc * 64 + n * 16 + l15) * 64 + cb);
        #pragma unroll
        for (int m = 0; m < 4; ++m)
            #pragma unroll
            for (int n = 0; n < 4; ++n)
                acc[m][n] = mfma16(af[m], bf[n], acc[m][n]);
    }
}

// ---------------------------------------------------------------------------
// Projection GEMM: Y = A @ W.T, A fp32 [16384][768], Wimg fp16 swizzled image.
// A: reg-stage fp32 -> cvt -> swizzled ds_write (T14 async split).
// B: global_load_lds from pre-swizzled image. BK=64, dbuf, vmcnt(4) counted.
// MODE 0: Qh linear [bh][n][d], scaled. MODE 1: K half of KVimg.
// MODE 3: V half of KVimg.   KVimg tile: [bh*32+kt][24576]: K at key*192+swz(d),
// V at 12288 + d*64 + swz(key).
// ---------------------------------------------------------------------------
template<int MODE>
__global__ __launch_bounds__(256, 2)
void gemm_a32(const float* __restrict__ A, const _Float16* __restrict__ Wimg,
              _Float16* __restrict__ Y, float scale)
{
    __shared__ __attribute__((aligned(16))) _Float16 As[2][8192];
    __shared__ __attribute__((aligned(16))) _Float16 Bs[2][8192];

    const int tid  = threadIdx.x;
    const int wid  = tid >> 6;
    const int lane = tid & 63;
    const int l15  = lane & 15;
    const int l4   = lane >> 4;
    const int wr   = wid >> 1;
    const int wc   = wid & 1;
    const int m0   = blockIdx.x * 128;
    const int nt   = blockIdx.y;

    const unsigned char* Wt = (const unsigned char*)(Wimg + (size_t)nt * 12 * 8192);

    f32x4 acc[4][4];
    #pragma unroll
    for (int m = 0; m < 4; ++m)
        #pragma unroll
        for (int n = 0; n < 4; ++n)
            acc[m][n] = (f32x4){0.f, 0.f, 0.f, 0.f};

    // staging geometry: thread p-th chunk: linear = p*256+tid, row=linear>>4,
    // qcol = (linear&15)*4  (A fp32: 8 float4/thread per 128x64 tile)
    float4 rA[8];
    #pragma unroll
    for (int p = 0; p < 8; ++p) {
        const int linear = p * 256 + tid;
        const int row = linear >> 4, qc = (linear & 15) * 4;
        rA[p] = *(const float4*)(A + (size_t)(m0 + row) * DIMC + qc);
    }
    #pragma unroll
    for (int s = 0; s < 4; ++s)
        gl16(Wt + (size_t)(s * 256 + tid) * 16, &Bs[0][(s * 256 + tid) * 8]);

    for (int t = 0; t < 12; ++t) {
        const int cur = t & 1;
        if (t < 11) {
            const unsigned char* Wn = Wt + (size_t)(t + 1) * 16384;
            #pragma unroll
            for (int s = 0; s < 4; ++s)
                gl16(Wn + (size_t)(s * 256 + tid) * 16, &Bs[cur ^ 1][(s * 256 + tid) * 8]);
            asm volatile("s_waitcnt vmcnt(4)" ::: "memory");
        } else {
            asm volatile("s_waitcnt vmcnt(0)" ::: "memory");
        }
        // cvt + swizzled ds_write of A(t)
        #pragma unroll
        for (int p = 0; p < 8; ++p) {
            const int linear = p * 256 + tid;
            const int row = linear >> 4, qc = (linear & 15) * 4;
            f16x4 h = {(_Float16)rA[p].x, (_Float16)rA[p].y,
                       (_Float16)rA[p].z, (_Float16)rA[p].w};
            *(f16x4*)(&As[cur][row * 64 + (qc ^ ((row & 7) << 3))]) = h;
        }
        // issue A(t+1) loads (latency hides under compute of t)
        if (t < 11) {
            #pragma unroll
            for (int p = 0; p < 8; ++p) {
                const int linear = p * 256 + tid;
                const int row = linear >> 4, qc = (linear & 15) * 4;
                rA[p] = *(const float4*)(A + (size_t)(m0 + row) * DIMC + (t + 1) * 64 + qc);
            }
        }
        asm volatile("s_waitcnt lgkmcnt(0)" ::: "memory");
        __builtin_amdgcn_s_barrier();

        gemm_compute(&As[cur][0], &Bs[cur][0], wr, wc, l15, l4, acc);

        __builtin_amdgcn_s_barrier();
    }

    // epilogue
    #pragma unroll
    for (int m = 0; m < 4; ++m) {
        const int rbase = m0 + wr * 64 + m * 16 + l4 * 4;
        #pragma unroll
        for (int n = 0; n < 4; ++n) {
            const int c = nt * 128 + wc * 64 + n * 16 + l15;
            const int h = c / HD;
            const int d = c - h * HD;
            #pragma unroll
            for (int j = 0; j < 4; ++j) {
                const int r   = rbase + j;
                const int b   = r >> 11;
                const int nn  = r & (SEQ - 1);
                const int kt  = nn >> 6;
                const int key = nn & 63;
                size_t idx;
                if (MODE == 0)
                    idx = ((size_t)(b * NH + h) * SEQ + nn) * HD + d;
                else {
                    const size_t tb = ((size_t)(b * NH + h) * 32 + kt) * 24576;
                    if (MODE == 1)
                        idx = tb + (size_t)key * HD + (d ^ ((key & 7) << 3));
                    else
                        idx = tb + 12288 + (size_t)d * 64 + (key ^ ((d & 7) << 3));
                }
                Y[idx] = (_Float16)(acc[m][n][j] * scale);
            }
        }
    }
}

// ---------------------------------------------------------------------------
// Final GEMM: out = Ximg @ Wp.T + bias, both operands fp16 swizzled images,
// both staged via global_load_lds. vmcnt(8) counted.
// ---------------------------------------------------------------------------
__global__ __launch_bounds__(256, 2)
void gemm_x(const _Float16* __restrict__ Ximg, const _Float16* __restrict__ Wimg,
            float* __restrict__ out, const float* __restrict__ bias)
{
    __shared__ __attribute__((aligned(16))) _Float16 As[2][8192];
    __shared__ __attribute__((aligned(16))) _Float16 Bs[2][8192];

    const int tid  = threadIdx.x;
    const int wid  = tid >> 6;
    const int lane = tid & 63;
    const int l15  = lane & 15;
    const int l4   = lane >> 4;
    const int wr   = wid >> 1;
    const int wc   = wid & 1;
    const int mt   = blockIdx.x;
    const int nt   = blockIdx.y;

    const unsigned char* Xt = (const unsigned char*)(Ximg + (size_t)mt * 12 * 8192);
    const unsigned char* Wt = (const unsigned char*)(Wimg + (size_t)nt * 12 * 8192);

    f32x4 acc[4][4];
    #pragma unroll
    for (int m = 0; m < 4; ++m)
        #pragma unroll
        for (int n = 0; n < 4; ++n)
            acc[m][n] = (f32x4){0.f, 0.f, 0.f, 0.f};

    #pragma unroll
    for (int s = 0; s < 4; ++s) {
        gl16(Xt + (size_t)(s * 256 + tid) * 16, &As[0][(s * 256 + tid) * 8]);
        gl16(Wt + (size_t)(s * 256 + tid) * 16, &Bs[0][(s * 256 + tid) * 8]);
    }

    for (int t = 0; t < 12; ++t) {
        const int cur = t & 1;
        if (t < 11) {
            const unsigned char* Xn = Xt + (size_t)(t + 1) * 16384;
            const unsigned char* Wn = Wt + (size_t)(t + 1) * 16384;
            #pragma unroll
            for (int s = 0; s < 4; ++s) {
                gl16(Xn + (size_t)(s * 256 + tid) * 16, &As[cur ^ 1][(s * 256 + tid) * 8]);
                gl16(Wn + (size_t)(s * 256 + tid) * 16, &Bs[cur ^ 1][(s * 256 + tid) * 8]);
            }
            asm volatile("s_waitcnt vmcnt(8)" ::: "memory");
        } else {
            asm volatile("s_waitcnt vmcnt(0)" ::: "memory");
        }
        __builtin_amdgcn_s_barrier();

        gemm_compute(&As[cur][0], &Bs[cur][0], wr, wc, l15, l4, acc);

        __builtin_amdgcn_s_barrier();
    }

    #pragma unroll
    for (int m = 0; m < 4; ++m) {
        const int rbase = mt * 128 + wr * 64 + m * 16 + l4 * 4;
        #pragma unroll
        for (int n = 0; n < 4; ++n) {
            const int c = nt * 128 + wc * 64 + n * 16 + l15;
            const float bv = bias[c];
            #pragma unroll
            for (int j = 0; j < 4; ++j)
                out[(size_t)(rbase + j) * DIMC + c] = acc[m][n][j] + bv;
        }
    }
}

// ---------------------------------------------------------------------------
// Flash attention: 1024 threads = 16 waves (16 q-rows each), grid 256 (1/CU),
// q-tile 256. K/V double-buffered combined 48KB tile via global_load_lds from
// pre-swizzled KVimg. Counted vmcnt(3). exp2-domain softmax (Q pre-scaled by
// SCALE*log2e), defer-max THR=8. X written as pre-swizzled image for gemm_x.
// ---------------------------------------------------------------------------
__global__ __launch_bounds__(1024, 4)
void attn3(const _Float16* __restrict__ Qh, const _Float16* __restrict__ KVimg,
           _Float16* __restrict__ Ximg)
{
    __shared__ __attribute__((aligned(16))) _Float16 KV[2][24576]; // K:0..12288, V:12288..
    __shared__ __attribute__((aligned(16))) _Float16 Ps[16][16][72];

    const int tid  = threadIdx.x;
    const int wid  = tid >> 6;
    const int lane = tid & 63;
    const int l15  = lane & 15;
    const int l4   = lane >> 4;

    const int bid = blockIdx.x;
    const int swz = (bid & 7) * 32 + (bid >> 3);
    const int qt  = swz & 7;
    const int bh  = swz >> 3;

    const unsigned char* KVt = (const unsigned char*)KVimg + (size_t)bh * 32 * 49152;

    #pragma unroll
    for (int s = 0; s < 3; ++s)
        gl16(KVt + (size_t)(s * 1024 + tid) * 16, &KV[0][(size_t)(s * 1024 + tid) * 8]);

    const int q0 = qt * 256 + wid * 16;
    const size_t qbase = (size_t)bh * SEQ * HD;
    f16x8 qf[6];
    #pragma unroll
    for (int kk = 0; kk < 6; ++kk)
        qf[kk] = *(const f16x8*)(Qh + qbase + (size_t)(q0 + l15) * HD + kk * 32 + l4 * 8);

    f32x4 Oacc[12];
    #pragma unroll
    for (int nd = 0; nd < 12; ++nd)
        Oacc[nd] = (f32x4){0.f, 0.f, 0.f, 0.f};
    float mrow[4], lrow[4];
    #pragma unroll
    for (int j = 0; j < 4; ++j) { mrow[j] = -1e30f; lrow[j] = 0.f; }

    for (int kt = 0; kt < SEQ / 64; ++kt) {
        const int cur = kt & 1;
        if (kt < SEQ / 64 - 1) {
            const unsigned char* KVn = KVt + (size_t)(kt + 1) * 49152;
            #pragma unroll
            for (int s = 0; s < 3; ++s)
                gl16(KVn + (size_t)(s * 1024 + tid) * 16,
                     &KV[cur ^ 1][(size_t)(s * 1024 + tid) * 8]);
            asm volatile("s_waitcnt vmcnt(3)" ::: "memory");
        } else {
            asm volatile("s_waitcnt vmcnt(0)" ::: "memory");
        }
        __builtin_amdgcn_s_barrier();
        __builtin_amdgcn_sched_barrier(0);

        const _Float16* Kc = &KV[cur][0];
        const _Float16* Vc = &KV[cur][12288];

        // ---- S = Q K^T ----
        f32x4 sacc[4];
        #pragma unroll
        for (int nn = 0; nn < 4; ++nn)
            sacc[nn] = (f32x4){0.f, 0.f, 0.f, 0.f};
        __builtin_amdgcn_s_setprio(1);
        #pragma unroll
        for (int kk = 0; kk < 6; ++kk) {
            const int cb = (kk * 32 + l4 * 8) ^ ((l15 & 7) << 3);
            #pragma unroll
            for (int nn = 0; nn < 4; ++nn) {
                const f16x8 kf = *(const f16x8*)(Kc + (size_t)(nn * 16 + l15) * HD + cb);
                sacc[nn] = mfma16(qf[kk], kf, sacc[nn]);
            }
        }
        __builtin_amdgcn_s_setprio(0);

        // ---- online softmax, log2 domain, defer-max ----
        float vmax[4];
        bool need = false;
        #pragma unroll
        for (int j = 0; j < 4; ++j) {
            float v = fmaxf(fmaxf(sacc[0][j], sacc[1][j]),
                            fmaxf(sacc[2][j], sacc[3][j]));
            v = fmaxf(v, __shfl_xor(v, 1));
            v = fmaxf(v, __shfl_xor(v, 2));
            v = fmaxf(v, __shfl_xor(v, 4));
            v = fmaxf(v, __shfl_xor(v, 8));
            vmax[j] = v;
            need |= (v > mrow[j] + DEFER_THR);
        }
        if (__any(need)) {
            #pragma unroll
            for (int j = 0; j < 4; ++j) {
                const float mnew = fmaxf(mrow[j], vmax[j]);
                const float f    = exp2_hw(mrow[j] - mnew);
                mrow[j] = mnew;
                lrow[j] *= f;
                #pragma unroll
                for (int nd = 0; nd < 12; ++nd)
                    Oacc[nd][j] *= f;
            }
        }
        #pragma unroll
        for (int j = 0; j < 4; ++j) {
            float ssum = 0.f;
            #pragma unroll
            for (int nn = 0; nn < 4; ++nn) {
                const float p = exp2_hw(sacc[nn][j] - mrow[j]);
                sacc[nn][j] = p;
                ssum += p;
            }
            ssum += __shfl_xor(ssum, 1);
            ssum += __shfl_xor(ssum, 2);
            ssum += __shfl_xor(ssum, 4);
            ssum += __shfl_xor(ssum, 8);
            lrow[j] += ssum;
        }

        // P (C-frag) -> per-wave LDS -> reread as A-frags
        #pragma unroll
        for (int nn = 0; nn < 4; ++nn)
            #pragma unroll
            for (int j = 0; j < 4; ++j)
                Ps[wid][l4 * 4 + j][nn * 16 + l15] = (_Float16)sacc[nn][j];
        asm volatile("s_waitcnt lgkmcnt(0)" ::: "memory");
        __builtin_amdgcn_sched_barrier(0);

        // ---- O += P V ----
        __builtin_amdgcn_s_setprio(1);
        #pragma unroll
        for (int kk2 = 0; kk2 < 2; ++kk2) {
            const f16x8 pf = *(const f16x8*)(&Ps[wid][l15][kk2 * 32 + l4 * 8]);
            const int cb = (kk2 * 32 + l4 * 8) ^ ((l15 & 7) << 3);
            #pragma unroll
            for (int nd = 0; nd < 12; ++nd) {
                const f16x8 vfr = *(const f16x8*)(Vc + (size_t)(nd * 16 + l15) * 64 + cb);
                Oacc[nd] = mfma16(pf, vfr, Oacc[nd]);
            }
        }
        __builtin_amdgcn_s_setprio(0);

        __builtin_amdgcn_s_barrier();
        __builtin_amdgcn_sched_barrier(0);
    }

    // finalize into pre-swizzled X image
    const int b = bh >> 2;
    const int h = bh & 3;
    #pragma unroll
    for (int j = 0; j < 4; ++j) {
        const float inv = 1.f / lrow[j];
        const int qrow = q0 + l4 * 4 + j;
        const int gr   = b * SEQ + qrow;
        const int mt   = gr >> 7;
        const int r    = gr & 127;
        #pragma unroll
        for (int nd = 0; nd < 12; ++nd) {
            const int gc = h * HD + nd * 16 + l15;
            const int kb = gc >> 6;
            const int c  = gc & 63;
            Ximg[((size_t)(mt * 12 + kb) * 128 + r) * 64 + (c ^ ((r & 7) << 3))] =
                (_Float16)(Oacc[nd][j] * inv);
        }
    }
}

// ---------------------------------------------------------------------------
extern "C" void kernel_launch(void* const* d_in, const int* in_sizes, int n_in,
                              void* d_out, int out_size, void* d_ws, size_t ws_size,
                              hipStream_t stream)
{
    const float* q  = (const float*)d_in[0];
    const float* k  = (const float*)d_in[1];
    const float* v  = (const float*)d_in[2];
    const float* Wq = (const float*)d_in[3];
    const float* Wk = (const float*)d_in[4];
    const float* Wv = (const float*)d_in[5];
    const float* Wp = (const float*)d_in[6];
    const float* bp = (const float*)d_in[7];

    const size_t HSZ  = (size_t)NBATCH * NH * SEQ * HD;  // 12,582,912
    const size_t WIMG = 6 * 12 * 8192;                   // 589,824 halves
    _Float16* Qh    = (_Float16*)d_ws;
    _Float16* KVimg = Qh + HSZ;          // 2*HSZ halves
    _Float16* Ximg  = KVimg + 2 * HSZ;
    _Float16* Wpimg = Ximg + HSZ;        // +WIMG halves -> ~101.8 MB total
    // Wq/Wk/Wv images live in d_out (read only before final GEMM writes it)
    _Float16* Wqimg = (_Float16*)d_out;
    _Float16* Wkimg = Wqimg + WIMG;
    _Float16* Wvimg = Wkimg + WIMG;

    dim3 blk(256);
    dim3 ggrid(128, 6);

    cvt_w<<<dim3(576, 4), blk, 0, stream>>>(Wq, Wk, Wv, Wp, Wqimg, Wkimg, Wvimg, Wpimg);
    gemm_a32<0><<<ggrid, blk, 0, stream>>>(q, Wqimg, Qh, SCALE_F * LOG2E);
    gemm_a32<1><<<ggrid, blk, 0, stream>>>(k, Wkimg, KVimg, 1.0f);
    gemm_a32<3><<<ggrid, blk, 0, stream>>>(v, Wvimg, KVimg, 1.0f);
    attn3<<<dim3(256), dim3(1024), 0, stream>>>(Qh, KVimg, Ximg);
    gemm_x<<<ggrid, blk, 0, stream>>>(Ximg, Wpimg, (float*)d_out, bp);
}